// Round 3
// baseline (2863.522 us; speedup 1.0000x reference)
//
#include <hip/hip_runtime.h>
#include <math.h>

// ---------------- problem constants ----------------
#define B_    32
#define Cd    256
#define SH    3
#define NHd   8
#define MLPD  1024
#define TOK   100352              // 32*56*56
#define NWIN  2048                // TOK/49
#define SCALE 0.1767766952966369f // 32^-0.5
#define EPS   1e-5f

// =====================================================================
// LayerNorm over C=256. One wave per token, 4 tokens/block.
// row0 = global token offset of this chunk; output is chunk-local rows.
// GATHER=true: token (global) gathers from shifted/windowed source in `in`.
// =====================================================================
template<bool GATHER>
__global__ __launch_bounds__(256) void ln_kernel(const float* __restrict__ in,
        const float* __restrict__ g, const float* __restrict__ bt,
        float* __restrict__ out, int row0)
{
    const int tid  = threadIdx.x;
    const int wave = tid >> 6, lane = tid & 63;
    const int tl   = blockIdx.x * 4 + wave;      // local token index
    const int t    = row0 + tl;                  // global token index
    int src = t;
    if (GATHER) {
        int w = t / 49, n = t - w * 49;
        int b = w >> 6, wi = (w >> 3) & 7, wj = w & 7;
        int r = n / 7, c = n - r * 7;
        int oh = wi * 7 + r + SH; if (oh >= 56) oh -= 56;
        int ow = wj * 7 + c + SH; if (ow >= 56) ow -= 56;
        src = b * 3136 + oh * 56 + ow;
    }
    const float4 v = *(const float4*)(in + (size_t)src * 256 + lane * 4);
    float s = v.x + v.y + v.z + v.w;
    float q = v.x*v.x + v.y*v.y + v.z*v.z + v.w*v.w;
    #pragma unroll
    for (int m = 32; m; m >>= 1) { s += __shfl_xor(s, m); q += __shfl_xor(q, m); }
    const float mean = s * (1.f/256.f);
    const float var  = q * (1.f/256.f) - mean * mean;
    const float inv  = rsqrtf(var + EPS);
    const float4 gv = *(const float4*)(g  + lane * 4);
    const float4 bv = *(const float4*)(bt + lane * 4);
    float4 o;
    o.x = (v.x - mean) * inv * gv.x + bv.x;
    o.y = (v.y - mean) * inv * gv.y + bv.y;
    o.z = (v.z - mean) * inv * gv.z + bv.z;
    o.w = (v.w - mean) * inv * gv.w + bv.w;
    *(float4*)(out + (size_t)tl * 256 + lane * 4) = o;
}

// =====================================================================
// fp32 GEMM: C = A[M,K] @ B[K,N] (+bias, + epilogue). M = gridDim.y*128.
// 128x128 tile, BK=8, 256 threads, 8x8 per thread (4+64 split micro-tiles).
// EPI: 0 = +bias, C chunk-local                        (QKV)
//      1 = +bias, window-reverse scatter (global row row0+lr) + residual
//          from res (full tensor), C full tensor       (proj -> d_out)
//      2 = +bias, exact GELU, C chunk-local            (MLP1)
//      3 = +bias, +res at global row row0+lr, C full   (MLP2 -> d_out)
// =====================================================================
template<int EPI>
__global__ __launch_bounds__(256) void gemm_k(const float* __restrict__ A,
        const float* __restrict__ Bm, const float* __restrict__ bias,
        const float* __restrict__ res, float* __restrict__ C,
        int N, int K, int row0)
{
    __shared__ float As[8][128];
    __shared__ float Bs[8][128];
    const int tid = threadIdx.x;
    const int n0 = blockIdx.x * 128;
    const int m0 = blockIdx.y * 128;
    const int tx = tid & 15, ty = tid >> 4;

    float acc[8][8] = {};

    const int arow = tid >> 1, akh = (tid & 1) * 4;
    const int brow = tid >> 5, bcol = (tid & 31) * 4;
    const float* Ap = A  + (size_t)(m0 + arow) * K + akh;
    const float* Bp = Bm + (size_t)brow * N + n0 + bcol;

    for (int k0 = 0; k0 < K; k0 += 8) {
        const float4 a = *(const float4*)(Ap + k0);
        const float4 b = *(const float4*)(Bp + (size_t)k0 * N);
        __syncthreads();
        As[akh+0][arow] = a.x; As[akh+1][arow] = a.y;
        As[akh+2][arow] = a.z; As[akh+3][arow] = a.w;
        *(float4*)&Bs[brow][bcol] = b;
        __syncthreads();
        #pragma unroll
        for (int k = 0; k < 8; ++k) {
            const float4 a0 = *(const float4*)&As[k][ty*4];
            const float4 a1 = *(const float4*)&As[k][ty*4 + 64];
            const float4 b0 = *(const float4*)&Bs[k][tx*4];
            const float4 b1 = *(const float4*)&Bs[k][tx*4 + 64];
            const float av[8] = {a0.x,a0.y,a0.z,a0.w,a1.x,a1.y,a1.z,a1.w};
            const float bv[8] = {b0.x,b0.y,b0.z,b0.w,b1.x,b1.y,b1.z,b1.w};
            #pragma unroll
            for (int i = 0; i < 8; ++i)
                #pragma unroll
                for (int j = 0; j < 8; ++j)
                    acc[i][j] += av[i] * bv[j];
        }
    }

    #pragma unroll
    for (int i = 0; i < 8; ++i) {
        const int lr = m0 + ty*4 + (i & 3) + ((i >> 2) << 6);   // local row
        size_t orow = (size_t)lr;               // row used for res/C indexing
        if (EPI == 1) {
            const int grow = row0 + lr;         // global (windowed) token
            int w = grow / 49, n = grow - w * 49;
            int b = w >> 6, wi = (w >> 3) & 7, wj = w & 7;
            int r = n / 7, cc = n - r * 7;
            int oh = wi * 7 + r + SH;  if (oh >= 56) oh -= 56;
            int ow = wj * 7 + cc + SH; if (ow >= 56) ow -= 56;
            orow = (size_t)(b * 3136 + oh * 56 + ow);
        } else if (EPI == 3) {
            orow = (size_t)(row0 + lr);
        }
        #pragma unroll
        for (int jg = 0; jg < 2; ++jg) {
            const int c = n0 + tx*4 + jg*64;
            float4 v;
            v.x = acc[i][jg*4+0]; v.y = acc[i][jg*4+1];
            v.z = acc[i][jg*4+2]; v.w = acc[i][jg*4+3];
            const float4 bb = *(const float4*)(bias + c);
            v.x += bb.x; v.y += bb.y; v.z += bb.z; v.w += bb.w;
            if (EPI == 2) {
                v.x = 0.5f*v.x*(1.f + erff(v.x*0.70710678118654752f));
                v.y = 0.5f*v.y*(1.f + erff(v.y*0.70710678118654752f));
                v.z = 0.5f*v.z*(1.f + erff(v.z*0.70710678118654752f));
                v.w = 0.5f*v.w*(1.f + erff(v.w*0.70710678118654752f));
            }
            if (EPI == 1 || EPI == 3) {
                const float4 rv = *(const float4*)(res + orow * N + c);
                v.x += rv.x; v.y += rv.y; v.z += rv.z; v.w += rv.w;
            }
            *(float4*)(C + orow * N + c) = v;
        }
    }
}

// =====================================================================
// Windowed attention: block per (window-in-chunk, head). 256 threads.
// qkv chunk-local layout [CH,768]: q|k|v blocks of 256, head h at +h*32.
// o chunk-local [CH,256]. RPB index computed analytically.
// =====================================================================
__global__ __launch_bounds__(256) void attn_kernel(const float* __restrict__ qkv,
        const float* __restrict__ rpb, float* __restrict__ o)
{
    const int w = blockIdx.x;       // window within chunk
    const int h = blockIdx.y;       // head
    const int tid = threadIdx.x;

    __shared__ float qs[49*32];
    __shared__ float ks[49*32];
    __shared__ float vs[49*32];
    __shared__ float sc[49*49];

    for (int idx = tid; idx < 392; idx += 256) {
        const int row = idx >> 3, g4 = (idx & 7) * 4;
        const size_t base = (size_t)(w*49 + row) * 768 + h*32 + g4;
        float4 q = *(const float4*)(qkv + base);
        const float4 k = *(const float4*)(qkv + base + 256);
        const float4 v = *(const float4*)(qkv + base + 512);
        q.x *= SCALE; q.y *= SCALE; q.z *= SCALE; q.w *= SCALE;
        *(float4*)(qs + row*32 + g4) = q;
        *(float4*)(ks + row*32 + g4) = k;
        *(float4*)(vs + row*32 + g4) = v;
    }
    __syncthreads();

    for (int idx = tid; idx < 2401; idx += 256) {
        const int i = idx / 49, j = idx - i * 49;
        float s = 0.f;
        #pragma unroll
        for (int g = 0; g < 8; ++g) {
            const float4 a = *(const float4*)(qs + i*32 + g*4);
            const float4 b = *(const float4*)(ks + j*32 + g*4);
            s += a.x*b.x + a.y*b.y + a.z*b.z + a.w*b.w;
        }
        const int ri = i / 7, ci = i - ri*7;
        const int rj = j / 7, cj = j - rj*7;
        const int bidx = (ri - rj + 6) * 13 + (ci - cj + 6);
        sc[idx] = s + rpb[bidx * NHd + h];
    }
    __syncthreads();

    const int wv = tid >> 6, lane = tid & 63;
    for (int r = wv; r < 49; r += 4) {
        float x = (lane < 49) ? sc[r*49 + lane] : -INFINITY;
        float mx = x;
        #pragma unroll
        for (int m = 32; m; m >>= 1) mx = fmaxf(mx, __shfl_xor(mx, m));
        float e = (lane < 49) ? expf(x - mx) : 0.f;
        float sum = e;
        #pragma unroll
        for (int m = 32; m; m >>= 1) sum += __shfl_xor(sum, m);
        const float inv = 1.f / sum;
        if (lane < 49) sc[r*49 + lane] = e * inv;
    }
    __syncthreads();

    for (int idx = tid; idx < 392; idx += 256) {
        const int i = idx >> 3, d = (idx & 7) * 4;
        float4 acc = {0.f, 0.f, 0.f, 0.f};
        for (int j = 0; j < 49; ++j) {
            const float p = sc[i*49 + j];
            const float4 vv = *(const float4*)(vs + j*32 + d);
            acc.x += p * vv.x; acc.y += p * vv.y;
            acc.z += p * vv.z; acc.w += p * vv.w;
        }
        *(float4*)(o + (size_t)(w*49 + i) * 256 + h*32 + d) = acc;
    }
}

// =====================================================================
extern "C" void kernel_launch(void* const* d_in, const int* in_sizes, int n_in,
                              void* d_out, int out_size, void* d_ws, size_t ws_size,
                              hipStream_t stream)
{
    const float* x      = (const float*)d_in[0];
    const float* qkv_w  = (const float*)d_in[1];
    const float* qkv_b  = (const float*)d_in[2];
    const float* proj_w = (const float*)d_in[3];
    const float* proj_b = (const float*)d_in[4];
    const float* rpb    = (const float*)d_in[5];
    const float* n1g    = (const float*)d_in[6];
    const float* n1b    = (const float*)d_in[7];
    const float* n2g    = (const float*)d_in[8];
    const float* n2b    = (const float*)d_in[9];
    const float* w1     = (const float*)d_in[10];
    const float* b1     = (const float*)d_in[11];
    const float* w2     = (const float*)d_in[12];
    const float* b2     = (const float*)d_in[13];
    float* out = (float*)d_out;
    float* ws  = (float*)d_ws;

    // Pick chunk count (power of two, >=4 this round) so ws fits:
    // per-chunk floats = CH*1536 where CH = (NWIN/nch)*49 tokens.
    int nch = 4;
    while (nch < 16) {
        size_t ch = (size_t)(NWIN / nch) * 49;
        if (ch * 1536 * 4 <= ws_size) break;
        nch *= 2;
    }
    const int WCH = NWIN / nch;           // windows per chunk
    const int CH  = WCH * 49;             // tokens per chunk (div by 128 for nch<=16)

    float* buf0 = ws;                          // [CH,256]  LN out
    float* buf1 = buf0 + (size_t)CH * 256;     // [CH,1024] qkv(768) / mlp-hidden(1024)
    float* buf2 = buf1 + (size_t)CH * 1024;    // [CH,256]  attn out

    // ---- stage A: LN1 -> QKV -> attn -> proj(+scatter+residual) -> d_out (x1)
    for (int c = 0; c < nch; ++c) {
        const int row0 = c * CH;
        ln_kernel<true><<<CH/4, 256, 0, stream>>>(x, n1g, n1b, buf0, row0);
        gemm_k<0><<<dim3(768/128, CH/128), 256, 0, stream>>>(buf0, qkv_w, qkv_b, nullptr, buf1, 768, 256, 0);
        attn_kernel<<<dim3(WCH, NHd), 256, 0, stream>>>(buf1, rpb, buf2);
        gemm_k<1><<<dim3(256/128, CH/128), 256, 0, stream>>>(buf2, proj_w, proj_b, x, out, 256, 256, row0);
    }
    // ---- stage B: LN2 -> MLP1(+GELU) -> MLP2(+residual, in-place) -> d_out
    for (int c = 0; c < nch; ++c) {
        const int row0 = c * CH;
        ln_kernel<false><<<CH/4, 256, 0, stream>>>(out, n2g, n2b, buf0, row0);
        gemm_k<2><<<dim3(1024/128, CH/128), 256, 0, stream>>>(buf0, w1, b1, nullptr, buf1, 1024, 256, 0);
        gemm_k<3><<<dim3(256/128, CH/128), 256, 0, stream>>>(buf1, w2, b2, out, out, 256, 1024, row0);
    }
}

// Round 8
// 1195.766 us; speedup vs baseline: 2.3947x; 2.3947x over previous
//
#include <hip/hip_runtime.h>
#include <math.h>

// ---------------- problem constants ----------------
#define SH    3
#define NHd   8
#define TOK   100352              // 32*56*56
#define NWIN  2048                // TOK/49
#define SCALE 0.1767766952966369f // 32^-0.5
#define EPS   1e-5f

typedef __attribute__((ext_vector_type(8))) short short8;   // 8 bf16 (4 VGPR)
typedef __attribute__((ext_vector_type(4))) float f32x4;    // MFMA acc

// bf16 <-> f32 helpers (raw ushort bf16, RNE)
__device__ __forceinline__ unsigned short f2bf(float f) {
    unsigned x = __float_as_uint(f);
    x += 0x7FFFu + ((x >> 16) & 1u);
    return (unsigned short)(x >> 16);
}
__device__ __forceinline__ float b2f(unsigned short u) {
    return __uint_as_float(((unsigned)u) << 16);
}

__device__ __forceinline__ void gload16(const unsigned short* g, unsigned short* l) {
    __builtin_amdgcn_global_load_lds(
        (const __attribute__((address_space(1))) unsigned int*)g,
        (__attribute__((address_space(3))) unsigned int*)l, 16, 0, 0);
}

// =====================================================================
// Weight transpose + bf16 cast: w[K][N] f32 -> o[N][K] bf16. 32x32 tiles.
// =====================================================================
__global__ __launch_bounds__(256) void wtrans(const float* __restrict__ w,
        unsigned short* __restrict__ o, int K, int N)
{
    __shared__ float t[32][33];
    const int n0 = blockIdx.x * 32, k0 = blockIdx.y * 32;
    const int tr = threadIdx.x >> 5, tc = threadIdx.x & 31;
    #pragma unroll
    for (int i = 0; i < 4; ++i)
        t[tr + i*8][tc] = w[(size_t)(k0 + tr + i*8) * N + n0 + tc];
    __syncthreads();
    #pragma unroll
    for (int i = 0; i < 4; ++i)
        o[(size_t)(n0 + tr + i*8) * K + k0 + tc] = f2bf(t[tc][tr + i*8]);
}

// =====================================================================
// LayerNorm over C=256 (f32 in -> bf16 out). One wave/token, 4/block.
// GATHER: shifted-window gather for LN1.
// =====================================================================
template<bool GATHER>
__global__ __launch_bounds__(256) void ln_kernel(const float* __restrict__ in,
        const float* __restrict__ g, const float* __restrict__ bt,
        unsigned short* __restrict__ out, int row0)
{
    const int tid  = threadIdx.x;
    const int wave = tid >> 6, lane = tid & 63;
    const int tl   = blockIdx.x * 4 + wave;
    const int t    = row0 + tl;
    int src = t;
    if (GATHER) {
        int w = t / 49, n = t - w * 49;
        int b = w >> 6, wi = (w >> 3) & 7, wj = w & 7;
        int r = n / 7, c = n - r * 7;
        int oh = wi * 7 + r + SH; if (oh >= 56) oh -= 56;
        int ow = wj * 7 + c + SH; if (ow >= 56) ow -= 56;
        src = b * 3136 + oh * 56 + ow;
    }
    const float4 v = *(const float4*)(in + (size_t)src * 256 + lane * 4);
    float s = v.x + v.y + v.z + v.w;
    float q = v.x*v.x + v.y*v.y + v.z*v.z + v.w*v.w;
    #pragma unroll
    for (int m = 32; m; m >>= 1) { s += __shfl_xor(s, m); q += __shfl_xor(q, m); }
    const float mean = s * (1.f/256.f);
    const float var  = q * (1.f/256.f) - mean * mean;
    const float inv  = rsqrtf(var + EPS);
    const float4 gv = *(const float4*)(g  + lane * 4);
    const float4 bv = *(const float4*)(bt + lane * 4);
    ushort4 o;
    o.x = f2bf((v.x - mean) * inv * gv.x + bv.x);
    o.y = f2bf((v.y - mean) * inv * gv.y + bv.y);
    o.z = f2bf((v.z - mean) * inv * gv.z + bv.z);
    o.w = f2bf((v.w - mean) * inv * gv.w + bv.w);
    *(ushort4*)(out + (size_t)tl * 256 + lane * 4) = o;
}

// =====================================================================
// bf16 MFMA GEMM (m97 structure): C = A[M,K] @ Bt[N,K]^T (+bias+epilogue)
// 128x128 tile, K_STEP=32, 4 waves (each 64x64), 16 MFMA/K-step/wave.
// EPI: 0 = +bias -> bf16 chunk-local                 (QKV)
//      1 = +bias, window-reverse scatter + res(x f32) -> f32 global (proj)
//      2 = +bias, exact GELU -> bf16 chunk-local     (MLP1)
//      3 = +bias, +res at global row -> f32 global   (MLP2, in-place d_out)
// =====================================================================
template<int EPI>
__global__ __launch_bounds__(256) void mfma_gemm(
        const unsigned short* __restrict__ A, const unsigned short* __restrict__ Bt,
        const float* __restrict__ bias, const float* __restrict__ res,
        void* __restrict__ Cout, int N, int K, int row0)
{
    __shared__ alignas(16) unsigned short As[128 * 32];
    __shared__ alignas(16) unsigned short Bs[128 * 32];
    const int tid = threadIdx.x;
    const int wv = tid >> 6, ln = tid & 63;
    const int n0 = blockIdx.x * 128, m0 = blockIdx.y * 128;
    const int wr = (wv >> 1) * 64, wc = (wv & 1) * 64;

    f32x4 acc[4][4] = {};

    for (int k0 = 0; k0 < K; k0 += 32) {
        __syncthreads();                    // prev iter done reading LDS
        #pragma unroll
        for (int j = 0; j < 2; ++j) {
            const int c = j * 256 + wv * 64 + ln;     // 16B chunk id (0..511)
            const int r = c >> 2, ko = (c & 3) * 8;
            gload16(A  + (size_t)(m0 + r) * K + k0 + ko, As + c * 8);
            gload16(Bt + (size_t)(n0 + r) * K + k0 + ko, Bs + c * 8);
        }
        __syncthreads();                    // drains vmcnt -> LDS ready

        const int fr = ln & 15, fk = (ln >> 4) * 8;
        short8 af[4], bf[4];
        #pragma unroll
        for (int m = 0; m < 4; ++m)
            af[m] = *(const short8*)(As + (wr + m*16 + fr) * 32 + fk);
        #pragma unroll
        for (int n = 0; n < 4; ++n)
            bf[n] = *(const short8*)(Bs + (wc + n*16 + fr) * 32 + fk);
        #pragma unroll
        for (int m = 0; m < 4; ++m)
            #pragma unroll
            for (int n = 0; n < 4; ++n)
                acc[m][n] = __builtin_amdgcn_mfma_f32_16x16x32_bf16(
                                af[m], bf[n], acc[m][n], 0, 0, 0);
    }

    // epilogue: D row = (lane>>4)*4 + reg, col = lane&15  (per 16x16 tile)
    const int fr = ln & 15, fq = ln >> 4;
    #pragma unroll
    for (int m = 0; m < 4; ++m) {
        #pragma unroll
        for (int r = 0; r < 4; ++r) {
            const int lr = m0 + wr + m*16 + fq*4 + r;   // chunk-local row
            size_t orow = (size_t)lr;
            if (EPI == 1) {
                const int grow = row0 + lr;
                int w = grow / 49, n = grow - w * 49;
                int b = w >> 6, wi = (w >> 3) & 7, wj = w & 7;
                int rr = n / 7, cc = n - rr * 7;
                int oh = wi * 7 + rr + SH;  if (oh >= 56) oh -= 56;
                int ow = wj * 7 + cc + SH;  if (ow >= 56) ow -= 56;
                orow = (size_t)(b * 3136 + oh * 56 + ow);
            } else if (EPI == 3) {
                orow = (size_t)(row0 + lr);
            }
            #pragma unroll
            for (int n = 0; n < 4; ++n) {
                const int col = n0 + wc + n*16 + fr;
                float v = acc[m][n][r] + bias[col];
                if (EPI == 2)
                    v = 0.5f * v * (1.f + erff(v * 0.70710678118654752f));
                if (EPI == 1 || EPI == 3)
                    v += res[orow * (size_t)N + col];
                if (EPI == 0 || EPI == 2)
                    ((unsigned short*)Cout)[(size_t)lr * N + col] = f2bf(v);
                else
                    ((float*)Cout)[orow * (size_t)N + col] = v;
            }
        }
    }
}

// =====================================================================
// Windowed attention (fp32 math, bf16 in/out). Block per (window, head).
// qkv chunk-local [CH,768] bf16; o chunk-local [CH,256] bf16.
// =====================================================================
__global__ __launch_bounds__(256) void attn_kernel(const unsigned short* __restrict__ qkv,
        const float* __restrict__ rpb, unsigned short* __restrict__ o)
{
    const int w = blockIdx.x, h = blockIdx.y;
    const int tid = threadIdx.x;

    __shared__ float qs[49*32];
    __shared__ float ks[49*32];
    __shared__ float vs[49*32];
    __shared__ float sc[49*49];

    for (int idx = tid; idx < 392; idx += 256) {
        const int row = idx >> 3, g4 = (idx & 7) * 4;
        const size_t base = (size_t)(w*49 + row) * 768 + h*32 + g4;
        const ushort4 qu = *(const ushort4*)(qkv + base);
        const ushort4 ku = *(const ushort4*)(qkv + base + 256);
        const ushort4 vu = *(const ushort4*)(qkv + base + 512);
        qs[row*32 + g4+0] = b2f(qu.x) * SCALE;
        qs[row*32 + g4+1] = b2f(qu.y) * SCALE;
        qs[row*32 + g4+2] = b2f(qu.z) * SCALE;
        qs[row*32 + g4+3] = b2f(qu.w) * SCALE;
        ks[row*32 + g4+0] = b2f(ku.x); ks[row*32 + g4+1] = b2f(ku.y);
        ks[row*32 + g4+2] = b2f(ku.z); ks[row*32 + g4+3] = b2f(ku.w);
        vs[row*32 + g4+0] = b2f(vu.x); vs[row*32 + g4+1] = b2f(vu.y);
        vs[row*32 + g4+2] = b2f(vu.z); vs[row*32 + g4+3] = b2f(vu.w);
    }
    __syncthreads();

    for (int idx = tid; idx < 2401; idx += 256) {
        const int i = idx / 49, j = idx - i * 49;
        float s = 0.f;
        #pragma unroll
        for (int g = 0; g < 8; ++g) {
            const float4 a = *(const float4*)(qs + i*32 + g*4);
            const float4 b = *(const float4*)(ks + j*32 + g*4);
            s += a.x*b.x + a.y*b.y + a.z*b.z + a.w*b.w;
        }
        const int ri = i / 7, ci = i - ri*7;
        const int rj = j / 7, cj = j - rj*7;
        sc[idx] = s + rpb[((ri - rj + 6) * 13 + (ci - cj + 6)) * NHd + h];
    }
    __syncthreads();

    const int wv = tid >> 6, lane = tid & 63;
    for (int r = wv; r < 49; r += 4) {
        float xx = (lane < 49) ? sc[r*49 + lane] : -INFINITY;
        float mx = xx;
        #pragma unroll
        for (int m = 32; m; m >>= 1) mx = fmaxf(mx, __shfl_xor(mx, m));
        float e = (lane < 49) ? expf(xx - mx) : 0.f;
        float sum = e;
        #pragma unroll
        for (int m = 32; m; m >>= 1) sum += __shfl_xor(sum, m);
        const float inv = 1.f / sum;
        if (lane < 49) sc[r*49 + lane] = e * inv;
    }
    __syncthreads();

    for (int idx = tid; idx < 392; idx += 256) {
        const int i = idx >> 3, d = (idx & 7) * 4;
        float4 acc = {0.f, 0.f, 0.f, 0.f};
        for (int j = 0; j < 49; ++j) {
            const float p = sc[i*49 + j];
            const float4 vv = *(const float4*)(vs + j*32 + d);
            acc.x += p * vv.x; acc.y += p * vv.y;
            acc.z += p * vv.z; acc.w += p * vv.w;
        }
        ushort4 ou;
        ou.x = f2bf(acc.x); ou.y = f2bf(acc.y);
        ou.z = f2bf(acc.z); ou.w = f2bf(acc.w);
        *(ushort4*)(o + (size_t)(w*49 + i) * 256 + h*32 + d) = ou;
    }
}

// =====================================================================
extern "C" void kernel_launch(void* const* d_in, const int* in_sizes, int n_in,
                              void* d_out, int out_size, void* d_ws, size_t ws_size,
                              hipStream_t stream)
{
    const float* x      = (const float*)d_in[0];
    const float* qkv_w  = (const float*)d_in[1];
    const float* qkv_b  = (const float*)d_in[2];
    const float* proj_w = (const float*)d_in[3];
    const float* proj_b = (const float*)d_in[4];
    const float* rpb    = (const float*)d_in[5];
    const float* n1g    = (const float*)d_in[6];
    const float* n1b    = (const float*)d_in[7];
    const float* n2g    = (const float*)d_in[8];
    const float* n2b    = (const float*)d_in[9];
    const float* w1     = (const float*)d_in[10];
    const float* b1     = (const float*)d_in[11];
    const float* w2     = (const float*)d_in[12];
    const float* b2     = (const float*)d_in[13];
    float* out = (float*)d_out;

    // workspace: bf16 transposed weights + per-chunk bf16 activation buffers
    const size_t WB = 768*256 + 256*256 + 1024*256 + 256*1024;   // 786432 els
    int nch = 4;
    while (nch < 16) {
        size_t CHt = (size_t)(NWIN / nch) * 49;
        if (WB * 2 + CHt * 3072 <= ws_size) break;
        nch *= 2;
    }
    const int WCH = NWIN / nch;
    const int CH  = WCH * 49;             // tokens/chunk, divisible by 128

    unsigned short* wq   = (unsigned short*)d_ws;
    unsigned short* wp   = wq  + 768*256;
    unsigned short* w1t  = wp  + 256*256;
    unsigned short* w2t  = w1t + 1024*256;
    unsigned short* buf0 = w2t + 256*1024;            // [CH,256]  LN out
    unsigned short* buf1 = buf0 + (size_t)CH * 256;   // [CH,1024] qkv/hidden
    unsigned short* buf2 = buf1 + (size_t)CH * 1024;  // [CH,256]  attn out

    // weights -> bf16 [N][K]
    wtrans<<<dim3(768/32, 256/32), 256, 0, stream>>>(qkv_w, wq, 256, 768);
    wtrans<<<dim3(256/32, 256/32), 256, 0, stream>>>(proj_w, wp, 256, 256);
    wtrans<<<dim3(1024/32, 256/32), 256, 0, stream>>>(w1, w1t, 256, 1024);
    wtrans<<<dim3(256/32, 1024/32), 256, 0, stream>>>(w2, w2t, 1024, 256);

    // stage A: LN1 -> QKV -> attn -> proj(+scatter+residual) -> d_out (=x1)
    for (int c = 0; c < nch; ++c) {
        const int row0 = c * CH;
        ln_kernel<true><<<CH/4, 256, 0, stream>>>(x, n1g, n1b, buf0, row0);
        mfma_gemm<0><<<dim3(6, CH/128), 256, 0, stream>>>(buf0, wq, qkv_b, nullptr, buf1, 768, 256, 0);
        attn_kernel<<<dim3(WCH, NHd), 256, 0, stream>>>(buf1, rpb, buf2);
        mfma_gemm<1><<<dim3(2, CH/128), 256, 0, stream>>>(buf2, wp, proj_b, x, out, 256, 256, row0);
    }
    // stage B: LN2 -> MLP1(+GELU) -> MLP2(+residual, in-place) -> d_out
    for (int c = 0; c < nch; ++c) {
        const int row0 = c * CH;
        ln_kernel<false><<<CH/4, 256, 0, stream>>>(out, n2g, n2b, buf0, row0);
        mfma_gemm<2><<<dim3(8, CH/128), 256, 0, stream>>>(buf0, w1t, b1, nullptr, buf1, 1024, 256, 0);
        mfma_gemm<3><<<dim3(2, CH/128), 256, 0, stream>>>(buf1, w2t, b2, out, out, 256, 1024, row0);
    }
}

// Round 11
// 887.451 us; speedup vs baseline: 3.2267x; 1.3474x over previous
//
#include <hip/hip_runtime.h>
#include <math.h>

// ---------------- problem constants ----------------
#define SH    3
#define NHd   8
#define TOK   100352              // 32*56*56
#define NWIN  2048                // TOK/49
#define SCALE 0.1767766952966369f // 32^-0.5
#define EPS   1e-5f

typedef __attribute__((ext_vector_type(8))) short short8;   // 8 bf16 (4 VGPR)
typedef __attribute__((ext_vector_type(4))) float f32x4;    // MFMA acc

// bf16 <-> f32 helpers (raw ushort bf16, RNE)
__device__ __forceinline__ unsigned short f2bf(float f) {
    unsigned x = __float_as_uint(f);
    x += 0x7FFFu + ((x >> 16) & 1u);
    return (unsigned short)(x >> 16);
}
__device__ __forceinline__ float b2f(unsigned short u) {
    return __uint_as_float(((unsigned)u) << 16);
}

__device__ __forceinline__ void gload16(const unsigned short* g, unsigned short* l) {
    __builtin_amdgcn_global_load_lds(
        (const __attribute__((address_space(1))) unsigned int*)g,
        (__attribute__((address_space(3))) unsigned int*)l, 16, 0, 0);
}

// =====================================================================
// Weight transpose + bf16 cast: w[K][N] f32 -> o[N][K] bf16. 32x32 tiles.
// =====================================================================
__global__ __launch_bounds__(256) void wtrans(const float* __restrict__ w,
        unsigned short* __restrict__ o, int K, int N)
{
    __shared__ float t[32][33];
    const int n0 = blockIdx.x * 32, k0 = blockIdx.y * 32;
    const int tr = threadIdx.x >> 5, tc = threadIdx.x & 31;
    #pragma unroll
    for (int i = 0; i < 4; ++i)
        t[tr + i*8][tc] = w[(size_t)(k0 + tr + i*8) * N + n0 + tc];
    __syncthreads();
    #pragma unroll
    for (int i = 0; i < 4; ++i)
        o[(size_t)(n0 + tr + i*8) * K + k0 + tc] = f2bf(t[tc][tr + i*8]);
}

// =====================================================================
// LayerNorm over C=256 (f32 in -> bf16 out). One wave/token, 4/block.
// GATHER: shifted-window gather for LN1.
// =====================================================================
template<bool GATHER>
__global__ __launch_bounds__(256) void ln_kernel(const float* __restrict__ in,
        const float* __restrict__ g, const float* __restrict__ bt,
        unsigned short* __restrict__ out, int row0)
{
    const int tid  = threadIdx.x;
    const int wave = tid >> 6, lane = tid & 63;
    const int tl   = blockIdx.x * 4 + wave;
    const int t    = row0 + tl;
    int src = t;
    if (GATHER) {
        int w = t / 49, n = t - w * 49;
        int b = w >> 6, wi = (w >> 3) & 7, wj = w & 7;
        int r = n / 7, c = n - r * 7;
        int oh = wi * 7 + r + SH; if (oh >= 56) oh -= 56;
        int ow = wj * 7 + c + SH; if (ow >= 56) ow -= 56;
        src = b * 3136 + oh * 56 + ow;
    }
    const float4 v = *(const float4*)(in + (size_t)src * 256 + lane * 4);
    float s = v.x + v.y + v.z + v.w;
    float q = v.x*v.x + v.y*v.y + v.z*v.z + v.w*v.w;
    #pragma unroll
    for (int m = 32; m; m >>= 1) { s += __shfl_xor(s, m); q += __shfl_xor(q, m); }
    const float mean = s * (1.f/256.f);
    const float var  = q * (1.f/256.f) - mean * mean;
    const float inv  = rsqrtf(var + EPS);
    const float4 gv = *(const float4*)(g  + lane * 4);
    const float4 bv = *(const float4*)(bt + lane * 4);
    ushort4 o;
    o.x = f2bf((v.x - mean) * inv * gv.x + bv.x);
    o.y = f2bf((v.y - mean) * inv * gv.y + bv.y);
    o.z = f2bf((v.z - mean) * inv * gv.z + bv.z);
    o.w = f2bf((v.w - mean) * inv * gv.w + bv.w);
    *(ushort4*)(out + (size_t)tl * 256 + lane * 4) = o;
}

// =====================================================================
// bf16 MFMA GEMM (m97 structure): C = A[M,K] @ Bt[N,K]^T (+bias+epilogue)
// 128x128 tile, K_STEP=32, 4 waves (each 64x64), 16 MFMA/K-step/wave.
// EPI: 0 = +bias -> bf16 chunk-local                 (QKV)
//      1 = +bias, window-reverse scatter + res(x f32) -> f32 global (proj)
//      2 = +bias, exact GELU -> bf16 chunk-local     (MLP1)
//      3 = +bias, +res at global row -> f32 global   (MLP2, in-place d_out)
// =====================================================================
template<int EPI>
__global__ __launch_bounds__(256) void mfma_gemm(
        const unsigned short* __restrict__ A, const unsigned short* __restrict__ Bt,
        const float* __restrict__ bias, const float* __restrict__ res,
        void* __restrict__ Cout, int N, int K, int row0)
{
    __shared__ alignas(16) unsigned short As[128 * 32];
    __shared__ alignas(16) unsigned short Bs[128 * 32];
    const int tid = threadIdx.x;
    const int wv = tid >> 6, ln = tid & 63;
    const int n0 = blockIdx.x * 128, m0 = blockIdx.y * 128;
    const int wr = (wv >> 1) * 64, wc = (wv & 1) * 64;

    f32x4 acc[4][4] = {};

    for (int k0 = 0; k0 < K; k0 += 32) {
        __syncthreads();                    // prev iter done reading LDS
        #pragma unroll
        for (int j = 0; j < 2; ++j) {
            const int c = j * 256 + wv * 64 + ln;     // 16B chunk id (0..511)
            const int r = c >> 2, ko = (c & 3) * 8;
            gload16(A  + (size_t)(m0 + r) * K + k0 + ko, As + c * 8);
            gload16(Bt + (size_t)(n0 + r) * K + k0 + ko, Bs + c * 8);
        }
        __syncthreads();                    // drains vmcnt -> LDS ready

        const int fr = ln & 15, fk = (ln >> 4) * 8;
        short8 af[4], bf[4];
        #pragma unroll
        for (int m = 0; m < 4; ++m)
            af[m] = *(const short8*)(As + (wr + m*16 + fr) * 32 + fk);
        #pragma unroll
        for (int n = 0; n < 4; ++n)
            bf[n] = *(const short8*)(Bs + (wc + n*16 + fr) * 32 + fk);
        #pragma unroll
        for (int m = 0; m < 4; ++m)
            #pragma unroll
            for (int n = 0; n < 4; ++n)
                acc[m][n] = __builtin_amdgcn_mfma_f32_16x16x32_bf16(
                                af[m], bf[n], acc[m][n], 0, 0, 0);
    }

    // epilogue: D row = (lane>>4)*4 + reg, col = lane&15  (per 16x16 tile)
    const int fr = ln & 15, fq = ln >> 4;
    #pragma unroll
    for (int m = 0; m < 4; ++m) {
        #pragma unroll
        for (int r = 0; r < 4; ++r) {
            const int lr = m0 + wr + m*16 + fq*4 + r;   // chunk-local row
            size_t orow = (size_t)lr;
            if (EPI == 1) {
                const int grow = row0 + lr;
                int w = grow / 49, n = grow - w * 49;
                int b = w >> 6, wi = (w >> 3) & 7, wj = w & 7;
                int rr = n / 7, cc = n - rr * 7;
                int oh = wi * 7 + rr + SH;  if (oh >= 56) oh -= 56;
                int ow = wj * 7 + cc + SH;  if (ow >= 56) ow -= 56;
                orow = (size_t)(b * 3136 + oh * 56 + ow);
            } else if (EPI == 3) {
                orow = (size_t)(row0 + lr);
            }
            #pragma unroll
            for (int n = 0; n < 4; ++n) {
                const int col = n0 + wc + n*16 + fr;
                float v = acc[m][n][r] + bias[col];
                if (EPI == 2)
                    v = 0.5f * v * (1.f + erff(v * 0.70710678118654752f));
                if (EPI == 1 || EPI == 3)
                    v += res[orow * (size_t)N + col];
                if (EPI == 0 || EPI == 2)
                    ((unsigned short*)Cout)[(size_t)lr * N + col] = f2bf(v);
                else
                    ((float*)Cout)[orow * (size_t)N + col] = v;
            }
        }
    }
}

// =====================================================================
// MFMA windowed attention: one WAVE (64 thr) per (window, head).
// qkv chunk-local [CH,768] bf16 (q|k|v, head h at +h*32), o [CH,256] bf16.
// QK^T: S[64x64] = Q @ K^T  (HD=32 = one 16x16x32 MFMA K-step, 16 tiles)
// softmax: in-register, row spread over 16 lanes (shfl_xor 1/2/4/8)
// PV: O[64x32] = P @ V^T-staged, K=64 (2 steps, 16 MFMAs)
// NaN hygiene (round-9 bug): vt cols j>=49 zeroed; softmax mx/sum clamped
// so masked rows produce exact zeros (never -INF - -INF = NaN).
// =====================================================================
__global__ __launch_bounds__(64) void attn_mfma(const unsigned short* __restrict__ qkv,
        const float* __restrict__ rpb, unsigned short* __restrict__ o)
{
    const int w = blockIdx.x, h = blockIdx.y;
    const int ln = threadIdx.x;
    const int fr = ln & 15, fq = ln >> 4;
    const int fk8 = fq * 8;

    __shared__ alignas(16) unsigned short qs[64][40];
    __shared__ alignas(16) unsigned short ks[64][40];
    __shared__ alignas(16) unsigned short vt[32][88];
    __shared__ alignas(16) unsigned short ps[64][88];

    // stage q,k head slices (16B vector copies; rows 49..63 stale -> masked later)
    for (int t = ln; t < 392; t += 64) {
        const int mat = t / 196;               // 0=q, 1=k
        const int tt  = t - mat * 196;
        const int row = tt >> 2, c8 = (tt & 3) * 8;
        const short8 v = *(const short8*)(qkv + (size_t)(w*49 + row) * 768 + mat*256 + h*32 + c8);
        *(short8*)&(mat ? ks : qs)[row][c8] = v;
    }
    // stage v transposed: vt[d][j], j<49
    for (int t = ln; t < 392; t += 64) {
        const int row = t >> 3, d4 = (t & 7) * 4;
        const ushort4 v = *(const ushort4*)(qkv + (size_t)(w*49 + row) * 768 + 512 + h*32 + d4);
        vt[d4+0][row] = v.x; vt[d4+1][row] = v.y;
        vt[d4+2][row] = v.z; vt[d4+3][row] = v.w;
    }
    // zero vt padding cols j=49..63 (PV contracts over j=0..63; stale LDS may be NaN)
    for (int t = ln; t < 480; t += 64) {
        const int d = t / 15, j = 49 + t - d * 15;
        vt[d][j] = 0;
    }
    __syncthreads();

    // ---- QK^T (16 MFMAs, single K-step since HD=32)
    f32x4 sacc[4][4];
    {
        short8 af[4], bf[4];
        #pragma unroll
        for (int m = 0; m < 4; ++m) af[m] = *(const short8*)&qs[m*16 + fr][fk8];
        #pragma unroll
        for (int n = 0; n < 4; ++n) bf[n] = *(const short8*)&ks[n*16 + fr][fk8];
        const f32x4 z = {0.f, 0.f, 0.f, 0.f};
        #pragma unroll
        for (int m = 0; m < 4; ++m)
            #pragma unroll
            for (int n = 0; n < 4; ++n)
                sacc[m][n] = __builtin_amdgcn_mfma_f32_16x16x32_bf16(af[m], bf[n], z, 0, 0, 0);
    }

    // ---- softmax per row (rows i = m*16 + fq*4 + r; cols j = n*16 + fr)
    #pragma unroll
    for (int m = 0; m < 4; ++m) {
        #pragma unroll
        for (int r = 0; r < 4; ++r) {
            const int i = m*16 + fq*4 + r;
            float sv[4];
            #pragma unroll
            for (int n = 0; n < 4; ++n) {
                const int j = n*16 + fr;
                float s = -INFINITY;
                if (i < 49 && j < 49) {
                    const int ri = i / 7, ci = i - ri*7;
                    const int rj = j / 7, cj = j - rj*7;
                    s = sacc[m][n][r] * SCALE
                        + rpb[((ri - rj + 6) * 13 + (ci - cj + 6)) * NHd + h];
                }
                sv[n] = s;
            }
            float mx = fmaxf(fmaxf(sv[0], sv[1]), fmaxf(sv[2], sv[3]));
            #pragma unroll
            for (int d = 1; d < 16; d <<= 1) mx = fmaxf(mx, __shfl_xor(mx, d));
            mx = fmaxf(mx, -1e30f);            // masked rows: exp(-INF - mx) = 0, not NaN
            float e0 = __expf(sv[0]-mx), e1 = __expf(sv[1]-mx);
            float e2 = __expf(sv[2]-mx), e3 = __expf(sv[3]-mx);
            float sum = e0 + e1 + e2 + e3;
            #pragma unroll
            for (int d = 1; d < 16; d <<= 1) sum += __shfl_xor(sum, d);
            const float inv = 1.f / fmaxf(sum, 1e-37f);   // masked rows: 0*inv = 0
            ps[i][ 0 + fr] = f2bf(e0 * inv);
            ps[i][16 + fr] = f2bf(e1 * inv);
            ps[i][32 + fr] = f2bf(e2 * inv);
            ps[i][48 + fr] = f2bf(e3 * inv);
        }
    }
    __syncthreads();

    // ---- PV (K=64 over j, 2 steps x 4m x 2n = 16 MFMAs)
    f32x4 pacc[4][2] = {};
    #pragma unroll
    for (int kst = 0; kst < 2; ++kst) {
        short8 pa[4], vb[2];
        #pragma unroll
        for (int m = 0; m < 4; ++m) pa[m] = *(const short8*)&ps[m*16 + fr][kst*32 + fk8];
        #pragma unroll
        for (int n = 0; n < 2; ++n) vb[n] = *(const short8*)&vt[n*16 + fr][kst*32 + fk8];
        #pragma unroll
        for (int m = 0; m < 4; ++m)
            #pragma unroll
            for (int n = 0; n < 2; ++n)
                pacc[m][n] = __builtin_amdgcn_mfma_f32_16x16x32_bf16(pa[m], vb[n], pacc[m][n], 0, 0, 0);
    }

    // ---- store O (bf16 chunk-local)
    #pragma unroll
    for (int m = 0; m < 4; ++m) {
        #pragma unroll
        for (int r = 0; r < 4; ++r) {
            const int i = m*16 + fq*4 + r;
            if (i < 49) {
                #pragma unroll
                for (int n = 0; n < 2; ++n)
                    o[(size_t)(w*49 + i) * 256 + h*32 + n*16 + fr] = f2bf(pacc[m][n][r]);
            }
        }
    }
}

// =====================================================================
extern "C" void kernel_launch(void* const* d_in, const int* in_sizes, int n_in,
                              void* d_out, int out_size, void* d_ws, size_t ws_size,
                              hipStream_t stream)
{
    const float* x      = (const float*)d_in[0];
    const float* qkv_w  = (const float*)d_in[1];
    const float* qkv_b  = (const float*)d_in[2];
    const float* proj_w = (const float*)d_in[3];
    const float* proj_b = (const float*)d_in[4];
    const float* rpb    = (const float*)d_in[5];
    const float* n1g    = (const float*)d_in[6];
    const float* n1b    = (const float*)d_in[7];
    const float* n2g    = (const float*)d_in[8];
    const float* n2b    = (const float*)d_in[9];
    const float* w1     = (const float*)d_in[10];
    const float* b1     = (const float*)d_in[11];
    const float* w2     = (const float*)d_in[12];
    const float* b2     = (const float*)d_in[13];
    float* out = (float*)d_out;

    // workspace: bf16 transposed weights + per-chunk bf16 activation buffers
    const size_t WB = 768*256 + 256*256 + 1024*256 + 256*1024;   // 786432 els
    int nch = 1;                      // prefer 1 chunk; fall back if ws too small
    while (nch < 16) {
        size_t CHt = (size_t)(NWIN / nch) * 49;
        if (WB * 2 + CHt * 3072 <= ws_size) break;
        nch *= 2;
    }
    const int WCH = NWIN / nch;
    const int CH  = WCH * 49;             // tokens/chunk, divisible by 128

    unsigned short* wq   = (unsigned short*)d_ws;
    unsigned short* wp   = wq  + 768*256;
    unsigned short* w1t  = wp  + 256*256;
    unsigned short* w2t  = w1t + 1024*256;
    unsigned short* buf0 = w2t + 256*1024;            // [CH,256]  LN out
    unsigned short* buf1 = buf0 + (size_t)CH * 256;   // [CH,1024] qkv/hidden
    unsigned short* buf2 = buf1 + (size_t)CH * 1024;  // [CH,256]  attn out

    // weights -> bf16 [N][K]
    wtrans<<<dim3(768/32, 256/32), 256, 0, stream>>>(qkv_w, wq, 256, 768);
    wtrans<<<dim3(256/32, 256/32), 256, 0, stream>>>(proj_w, wp, 256, 256);
    wtrans<<<dim3(1024/32, 256/32), 256, 0, stream>>>(w1, w1t, 256, 1024);
    wtrans<<<dim3(256/32, 1024/32), 256, 0, stream>>>(w2, w2t, 1024, 256);

    // stage A: LN1 -> QKV -> attn -> proj(+scatter+residual) -> d_out (=x1)
    for (int c = 0; c < nch; ++c) {
        const int row0 = c * CH;
        ln_kernel<true><<<CH/4, 256, 0, stream>>>(x, n1g, n1b, buf0, row0);
        mfma_gemm<0><<<dim3(6, CH/128), 256, 0, stream>>>(buf0, wq, qkv_b, nullptr, buf1, 768, 256, 0);
        attn_mfma<<<dim3(WCH, NHd), 64, 0, stream>>>(buf1, rpb, buf2);
        mfma_gemm<1><<<dim3(2, CH/128), 256, 0, stream>>>(buf2, wp, proj_b, x, out, 256, 256, row0);
    }
    // stage B: LN2 -> MLP1(+GELU) -> MLP2(+residual, in-place) -> d_out
    for (int c = 0; c < nch; ++c) {
        const int row0 = c * CH;
        ln_kernel<false><<<CH/4, 256, 0, stream>>>(out, n2g, n2b, buf0, row0);
        mfma_gemm<2><<<dim3(8, CH/128), 256, 0, stream>>>(buf0, w1t, b1, nullptr, buf1, 1024, 256, 0);
        mfma_gemm<3><<<dim3(2, CH/128), 256, 0, stream>>>(buf1, w2t, b2, out, out, 256, 1024, row0);
    }
}